// Round 7
// baseline (1914.166 us; speedup 1.0000x reference)
//
#include <hip/hip_runtime.h>
#include <math.h>

#define NBLK 64

typedef __attribute__((ext_vector_type(8))) short short8;
typedef __attribute__((ext_vector_type(8))) _Float16 f16x8;
typedef __attribute__((ext_vector_type(4))) float f32x4;

__device__ __forceinline__ void split_f16(float f, unsigned short& h, unsigned short& l){
  _Float16 hh = (_Float16)f;
  _Float16 ll = (_Float16)(f - (float)hh);
  h = __builtin_bit_cast(unsigned short, hh);
  l = __builtin_bit_cast(unsigned short, ll);
}

__device__ __forceinline__ float fsig(float xv){            // 1/(1+e^-x)
  return 1.f / (1.f + __expf(-xv));
}
__device__ __forceinline__ float ftanh(float xv){           // 1 - 2/(1+e^2x)
  return 1.f - 2.f / (1.f + __expf(2.f * xv));
}

__global__ __launch_bounds__(256, 1) void lstm_persist(
    const float* __restrict__ x,
    const float* __restrict__ hidden0,
    const float* __restrict__ W_hid,
    const float* __restrict__ b_hid,
    const float* __restrict__ W_ih,
    const float* __restrict__ W_hh,
    const float* __restrict__ b_ih,
    const float* __restrict__ b_hh,
    float* __restrict__ out,
    float* __restrict__ out_h0,
    unsigned* __restrict__ flags,     // [64] one-time x-init barrier
    unsigned* __restrict__ hsteps,    // [256][32][512] packed (f16hi<<16|f16lo); 0xFFFFFFFF = not ready
    unsigned short* __restrict__ xhi, // [32][256][64] f16 bits
    unsigned short* __restrict__ xlo)
{
  const int tid  = threadIdx.x;
  const int bid  = blockIdx.x;
  const int lane = tid & 63;
  const int wid  = tid >> 6;   // 0..3
  const int cc   = wid & 1;    // batch half
  const int jh   = wid >> 1;   // j-half (4 cols each)
  const int m    = lane & 15;
  const int g    = lane >> 4;
  const int J0   = bid * 8;
  const int gid  = bid * 256 + tid;

  const int b_own = cc * 16 + m;        // C col (batch) this lane outputs; also B-frag batch
  const int j_own = J0 + jh * 4 + g;    // C rows g*4+q = gates q of this j
  // A-frag row rr = m, ordered rr = jj*4 + gate  ->  W row:
  const int RW = (m & 3) * 512 + J0 + jh * 4 + (m >> 2);

  // ---------------- init: h0 = hidden0 @ W_hid^T + b_hid ----------------
  {
    int b = gid >> 9, hc = gid & 511;
    const float* hv = hidden0 + b * 64;
    const float* wv = W_hid + hc * 64;
    float acc = b_hid[hc];
    #pragma unroll
    for (int d = 0; d < 64; d += 4){
      float4 a = *(const float4*)(hv + d);
      float4 w = *(const float4*)(wv + d);
      acc += a.x*w.x + a.y*w.y + a.z*w.z + a.w*w.w;
    }
    out_h0[gid] = acc;                       // second output
    unsigned short hh, ll; split_f16(acc, hh, ll);
    unsigned packed = ((unsigned)hh << 16) | (unsigned)ll;  // finite => hi16 != 0xFFFF
    asm volatile("global_store_dword %0, %1, off sc0 sc1" :: "v"(hsteps + gid), "v"(packed) : "memory");
  }
  // ---------------- init: x -> f16 hi/lo (write-through) ----------------
  {
    const float4* x4 = (const float4*)x;
    #pragma unroll
    for (int k = 0; k < 8; ++k){
      int v = gid + k * 16384;
      float4 f = x4[v];
      unsigned short ha,la,hb2,lb2,hc2,lc2,hd,ld;
      split_f16(f.x,ha,la); split_f16(f.y,hb2,lb2);
      split_f16(f.z,hc2,lc2); split_f16(f.w,hd,ld);
      uint2 ph, pl;
      ph.x = (unsigned)ha | ((unsigned)hb2 << 16);
      ph.y = (unsigned)hc2 | ((unsigned)hd << 16);
      pl.x = (unsigned)la | ((unsigned)lb2 << 16);
      pl.y = (unsigned)lc2 | ((unsigned)ld << 16);
      asm volatile("global_store_dwordx2 %0, %1, off sc0 sc1" :: "v"(xhi + (size_t)v*4), "v"(ph) : "memory");
      asm volatile("global_store_dwordx2 %0, %1, off sc0 sc1" :: "v"(xlo + (size_t)v*4), "v"(pl) : "memory");
    }
  }
  // ---------------- own c0, exact f32 ----------------
  float c_state;
  {
    const float* hv = hidden0 + b_own * 64;
    const float* wv = W_hid + j_own * 64;
    float acc = b_hid[j_own];
    #pragma unroll
    for (int d = 0; d < 64; d += 4){
      float4 a = *(const float4*)(hv + d);
      float4 w = *(const float4*)(wv + d);
      acc += a.x*w.x + a.y*w.y + a.z*w.z + a.w*w.w;
    }
    c_state = acc;
  }

  // ---------------- W_hh fragments -> registers (once) ----------------
  f16x8 whh_hi[16], whh_lo[16];
  #pragma unroll
  for (int kc = 0; kc < 16; ++kc){
    const float* p = W_hh + RW * 512 + kc * 32 + g * 8;
    float4 f0 = *(const float4*)p;
    float4 f1 = *(const float4*)(p + 4);
    float fs[8] = {f0.x,f0.y,f0.z,f0.w,f1.x,f1.y,f1.z,f1.w};
    short8 hb8, lb8;
    #pragma unroll
    for (int i = 0; i < 8; ++i){
      unsigned short hh, ll; split_f16(fs[i], hh, ll);
      hb8[i] = (short)hh; lb8[i] = (short)ll;
    }
    whh_hi[kc] = __builtin_bit_cast(f16x8, hb8);
    whh_lo[kc] = __builtin_bit_cast(f16x8, lb8);
  }

  const float bias_i = b_ih[j_own]        + b_hh[j_own];
  const float bias_f = b_ih[512 + j_own]  + b_hh[512 + j_own];
  const float bias_g = b_ih[1024 + j_own] + b_hh[1024 + j_own];
  const float bias_o = b_ih[1536 + j_own] + b_hh[1536 + j_own];

  // ---------------- one-time barrier: x f16 conversion complete ----------------
  asm volatile("s_waitcnt vmcnt(0)" ::: "memory");
  __syncthreads();
  if (tid == 0){
    unsigned one = 1;
    asm volatile("global_store_dword %0, %1, off sc0 sc1" :: "v"(flags + bid), "v"(one) : "memory");
  }
  {
    const unsigned* fp = flags + lane;
    while (true){
      unsigned fv;
      asm volatile("global_load_dword %0, %1, off sc0 sc1\n\ts_waitcnt vmcnt(0)"
                   : "=v"(fv) : "v"(fp) : "memory");
      if (__all((int)(fv >= 1u))) break;
      __builtin_amdgcn_s_sleep(1);
    }
  }

  // persistent x@W_ih prefix-sum accumulators (C-operand IS the cumsum)
  f32x4 axc0 = {0.f,0.f,0.f,0.f}, axc1 = axc0, axc2 = axc0;

  auto xpart = [&](int t){
    #pragma unroll
    for (int kc = 0; kc < 2; ++kc){
      const float* p = W_ih + (size_t)RW * 16384 + (size_t)t * 64 + kc * 32 + g * 8;
      float4 f0 = *(const float4*)p;
      float4 f1 = *(const float4*)(p + 4);
      float fs[8] = {f0.x,f0.y,f0.z,f0.w,f1.x,f1.y,f1.z,f1.w};
      short8 hb8, lb8;
      #pragma unroll
      for (int i = 0; i < 8; ++i){
        unsigned short hh, ll; split_f16(fs[i], hh, ll);
        hb8[i] = (short)hh; lb8[i] = (short)ll;
      }
      f16x8 ahi = __builtin_bit_cast(f16x8, hb8);
      f16x8 alo = __builtin_bit_cast(f16x8, lb8);
      size_t off = ((size_t)b_own * 256 + (size_t)t) * 64 + kc * 32 + g * 8;
      f16x8 bhi = __builtin_bit_cast(f16x8, *(const short8*)(xhi + off));
      f16x8 blo = __builtin_bit_cast(f16x8, *(const short8*)(xlo + off));
      axc0 = __builtin_amdgcn_mfma_f32_16x16x32_f16(ahi, bhi, axc0, 0,0,0);
      axc1 = __builtin_amdgcn_mfma_f32_16x16x32_f16(ahi, blo, axc1, 0,0,0);
      axc2 = __builtin_amdgcn_mfma_f32_16x16x32_f16(alo, bhi, axc2, 0,0,0);
    }
  };
  xpart(0);

  #define ISSUEC(KC) { \
    const unsigned* p_ = hb + (KC)*32 + g*8; \
    asm volatile("global_load_dwordx4 %0, %1, off sc0 sc1" : "=v"(ta[KC]) : "v"(p_)); \
    asm volatile("global_load_dwordx4 %0, %1, off sc0 sc1" : "=v"(tb[KC]) : "v"(p_+4)); }

  #define MX8(KC) { \
    unsigned a0_ = ta[KC].x > ta[KC].y ? ta[KC].x : ta[KC].y; \
    unsigned a1_ = ta[KC].z > ta[KC].w ? ta[KC].z : ta[KC].w; \
    unsigned b0_ = tb[KC].x > tb[KC].y ? tb[KC].x : tb[KC].y; \
    unsigned b1_ = tb[KC].z > tb[KC].w ? tb[KC].z : tb[KC].w; \
    unsigned c0_ = a0_ > a1_ ? a0_ : a1_; \
    unsigned c1_ = b0_ > b1_ ? b0_ : b1_; \
    unsigned d0_ = c0_ > c1_ ? c0_ : c1_; \
    mx = mx > d0_ ? mx : d0_; }

  #define CHECK_HALF(K0, WAITN) \
    asm volatile("s_waitcnt vmcnt(" WAITN ")" ::: "memory"); \
    __builtin_amdgcn_sched_barrier(0); \
    while (true){ \
      unsigned mx = 0u; \
      MX8((K0)+0) MX8((K0)+1) MX8((K0)+2) MX8((K0)+3) \
      MX8((K0)+4) MX8((K0)+5) MX8((K0)+6) MX8((K0)+7) \
      if (!__any((int)(mx == 0xFFFFFFFFu))) break; \
      ISSUEC((K0)+0) ISSUEC((K0)+1) ISSUEC((K0)+2) ISSUEC((K0)+3) \
      ISSUEC((K0)+4) ISSUEC((K0)+5) ISSUEC((K0)+6) ISSUEC((K0)+7) \
      asm volatile("s_waitcnt vmcnt(0)" ::: "memory"); \
      __builtin_amdgcn_sched_barrier(0); \
    }

  #define DOMFMA(KC) { \
    uint4 cA = ta[KC], cB = tb[KC]; \
    uint4 hiv, lov; \
    hiv.x = __builtin_amdgcn_perm(cA.y, cA.x, 0x07060302u); \
    hiv.y = __builtin_amdgcn_perm(cA.w, cA.z, 0x07060302u); \
    hiv.z = __builtin_amdgcn_perm(cB.y, cB.x, 0x07060302u); \
    hiv.w = __builtin_amdgcn_perm(cB.w, cB.z, 0x07060302u); \
    lov.x = __builtin_amdgcn_perm(cA.y, cA.x, 0x05040100u); \
    lov.y = __builtin_amdgcn_perm(cA.w, cA.z, 0x05040100u); \
    lov.z = __builtin_amdgcn_perm(cB.y, cB.x, 0x05040100u); \
    lov.w = __builtin_amdgcn_perm(cB.w, cB.z, 0x05040100u); \
    f16x8 bhi = __builtin_bit_cast(f16x8, hiv); \
    f16x8 blo = __builtin_bit_cast(f16x8, lov); \
    acc0 = __builtin_amdgcn_mfma_f32_16x16x32_f16(whh_hi[KC], bhi, acc0, 0,0,0); \
    acc1 = __builtin_amdgcn_mfma_f32_16x16x32_f16(whh_hi[KC], blo, acc1, 0,0,0); \
    acc2 = __builtin_amdgcn_mfma_f32_16x16x32_f16(whh_lo[KC], bhi, acc2, 0,0,0); }

  for (int t = 0; t < 256; ++t){
    const unsigned* hb = hsteps + (size_t)t * 16384 + (size_t)b_own * 512;
    uint4 ta[16], tb[16];

    // bulk-issue the whole B tile (32 dwordx4)
    ISSUEC(0)  ISSUEC(1)  ISSUEC(2)  ISSUEC(3)
    ISSUEC(4)  ISSUEC(5)  ISSUEC(6)  ISSUEC(7)
    ISSUEC(8)  ISSUEC(9)  ISSUEC(10) ISSUEC(11)
    ISSUEC(12) ISSUEC(13) ISSUEC(14) ISSUEC(15)

    f32x4 acc0 = {0.f,0.f,0.f,0.f}, acc1 = acc0, acc2 = acc0;

    CHECK_HALF(0, "16")           // chunks 0-7 arrived (16 newest may be in flight)
    DOMFMA(0) DOMFMA(1) DOMFMA(2) DOMFMA(3)
    DOMFMA(4) DOMFMA(5) DOMFMA(6) DOMFMA(7)

    CHECK_HALF(8, "0")
    DOMFMA(8)  DOMFMA(9)  DOMFMA(10) DOMFMA(11)
    DOMFMA(12) DOMFMA(13) DOMFMA(14) DOMFMA(15)

    // ---- gates entirely in-thread: acc regs q=0..3 are i,f,g,o of (b_own, j_own) ----
    f32x4 pre = acc0 + acc1 + acc2 + axc0 + axc1 + axc2;
    float ig = fsig(pre[0] + bias_i);
    float fg = fsig(pre[1] + bias_f);
    float gg = ftanh(pre[2] + bias_g);
    float og = fsig(pre[3] + bias_o);
    c_state = fg * c_state + ig * gg;
    float hval = og * ftanh(c_state);

    if (t < 255){
      unsigned short hh, ll; split_f16(hval, hh, ll);
      unsigned packed = ((unsigned)hh << 16) | (unsigned)ll;   // finite => hi16 != 0xFFFF
      asm volatile("global_store_dword %0, %1, off sc0 sc1"
                   :: "v"(hsteps + (size_t)(t+1)*16384 + (size_t)b_own*512 + j_own), "v"(packed) : "memory");
    }
    out[(size_t)(b_own * 256 + t) * 512 + j_own] = fmaxf(hval, 0.f);

    if (t < 255) xpart(t + 1);    // W_ih stream + cumsum MFMA fills the visibility window
  }
  #undef DOMFMA
  #undef CHECK_HALF
  #undef MX8
  #undef ISSUEC
}

// ---------------------------------------------------------------------------
extern "C" void kernel_launch(void* const* d_in, const int* in_sizes, int n_in,
                              void* d_out, int out_size, void* d_ws, size_t ws_size,
                              hipStream_t stream) {
  const float* x       = (const float*)d_in[0];
  const float* hidden0 = (const float*)d_in[1];
  const float* W_hid   = (const float*)d_in[2];
  const float* b_hid   = (const float*)d_in[3];
  const float* W_ih    = (const float*)d_in[4];
  const float* W_hh    = (const float*)d_in[5];
  const float* b_ih    = (const float*)d_in[6];
  const float* b_hh    = (const float*)d_in[7];

  float* out    = (float*)d_out;
  float* out_h0 = out + (size_t)32 * 256 * 512;

  char* ws = (char*)d_ws;
  unsigned*       flags  = (unsigned*)ws;                          // 256 B
  unsigned short* xhi    = (unsigned short*)(ws + 4096);           // 1 MB
  unsigned short* xlo    = (unsigned short*)(ws + 4096 + (1<<20)); // 1 MB
  unsigned*       hsteps = (unsigned*)(ws + 4096 + (2<<20));       // 16 MB: [256][32][512] dwords

  (void)hipMemsetAsync(flags, 0, 256, stream);
  (void)hipMemsetAsync(hsteps, 0xFF, (size_t)256 * 16384 * 4, stream);  // sentinel

  lstm_persist<<<NBLK, 256, 0, stream>>>(
      x, hidden0, W_hid, b_hid, W_ih, W_hh, b_ih, b_hh,
      out, out_h0, flags, hsteps, xhi, xlo);
}

// Round 8
// 845.161 us; speedup vs baseline: 2.2649x; 2.2649x over previous
//
#include <hip/hip_runtime.h>
#include <math.h>

#define NBLK 64

typedef __attribute__((ext_vector_type(8))) short short8;
typedef __attribute__((ext_vector_type(8))) _Float16 f16x8;
typedef __attribute__((ext_vector_type(4))) float f32x4;

__device__ __forceinline__ void split_f16(float f, unsigned short& h, unsigned short& l){
  _Float16 hh = (_Float16)f;
  _Float16 ll = (_Float16)(f - (float)hh);
  h = __builtin_bit_cast(unsigned short, hh);
  l = __builtin_bit_cast(unsigned short, ll);
}

__device__ __forceinline__ float fsig(float xv){ return 1.f / (1.f + __expf(-xv)); }
__device__ __forceinline__ float ftanh(float xv){ return 1.f - 2.f / (1.f + __expf(2.f * xv)); }

__global__ __launch_bounds__(256, 1) void lstm_persist(
    const float* __restrict__ x,
    const float* __restrict__ hidden0,
    const float* __restrict__ W_hid,
    const float* __restrict__ b_hid,
    const float* __restrict__ W_ih,
    const float* __restrict__ W_hh,
    const float* __restrict__ b_ih,
    const float* __restrict__ b_hh,
    float* __restrict__ out,
    float* __restrict__ out_h0,
    unsigned* __restrict__ flags,     // [64] one-time x-init barrier
    unsigned* __restrict__ hsteps,    // [256][32][512] packed (f16hi<<16|f16lo); 0xFFFFFFFF = not ready
    unsigned short* __restrict__ xhi, // [32][256][64] f16 bits
    unsigned short* __restrict__ xlo)
{
  __shared__ unsigned short hs_hi[2][16384];  // 2 x 32KB, [32 rows][64 units], XOR-swizzled
  __shared__ unsigned short hs_lo[2][16384];  // double-buffered by t&1 -> ONE barrier/step

  const int tid  = threadIdx.x;
  const int bid  = blockIdx.x;
  const int lane = tid & 63;
  const int wid  = tid >> 6;   // 0..3
  const int cc   = wid & 1;    // batch half
  const int jh   = wid >> 1;   // j-half (4 cols each)
  const int m    = lane & 15;
  const int g    = lane >> 4;
  const int J0   = bid * 8;
  const int gid  = bid * 256 + tid;

  const int b_own = cc * 16 + m;        // C col (batch); also B-frag batch row
  const int j_own = J0 + jh * 4 + g;    // C rows g*4+q = gates q of this j
  // A-row rr = m ordered rr = jj*4 + gate  ->  W_hh/W_ih row:
  const int RW = (m & 3) * 512 + J0 + jh * 4 + (m >> 2);

  // ---------------- init: h0 = hidden0 @ W_hid^T + b_hid ----------------
  {
    int b = gid >> 9, hc = gid & 511;
    const float* hv = hidden0 + b * 64;
    const float* wv = W_hid + hc * 64;
    float acc = b_hid[hc];
    #pragma unroll
    for (int d = 0; d < 64; d += 4){
      float4 a = *(const float4*)(hv + d);
      float4 w = *(const float4*)(wv + d);
      acc += a.x*w.x + a.y*w.y + a.z*w.z + a.w*w.w;
    }
    out_h0[gid] = acc;                       // second output
    unsigned short hh, ll; split_f16(acc, hh, ll);
    unsigned packed = ((unsigned)hh << 16) | (unsigned)ll;  // finite => hi16 != 0xFFFF
    asm volatile("global_store_dword %0, %1, off sc0 sc1" :: "v"(hsteps + gid), "v"(packed) : "memory");
  }
  // ---------------- init: x -> f16 hi/lo (write-through) ----------------
  {
    const float4* x4 = (const float4*)x;
    #pragma unroll
    for (int k = 0; k < 8; ++k){
      int v = gid + k * 16384;
      float4 f = x4[v];
      unsigned short ha,la,hb2,lb2,hc2,lc2,hd,ld;
      split_f16(f.x,ha,la); split_f16(f.y,hb2,lb2);
      split_f16(f.z,hc2,lc2); split_f16(f.w,hd,ld);
      uint2 ph, pl;
      ph.x = (unsigned)ha | ((unsigned)hb2 << 16);
      ph.y = (unsigned)hc2 | ((unsigned)hd << 16);
      pl.x = (unsigned)la | ((unsigned)lb2 << 16);
      pl.y = (unsigned)lc2 | ((unsigned)ld << 16);
      asm volatile("global_store_dwordx2 %0, %1, off sc0 sc1" :: "v"(xhi + (size_t)v*4), "v"(ph) : "memory");
      asm volatile("global_store_dwordx2 %0, %1, off sc0 sc1" :: "v"(xlo + (size_t)v*4), "v"(pl) : "memory");
    }
  }
  // ---------------- own c0, exact f32 ----------------
  float c_state;
  {
    const float* hv = hidden0 + b_own * 64;
    const float* wv = W_hid + j_own * 64;
    float acc = b_hid[j_own];
    #pragma unroll
    for (int d = 0; d < 64; d += 4){
      float4 a = *(const float4*)(hv + d);
      float4 w = *(const float4*)(wv + d);
      acc += a.x*w.x + a.y*w.y + a.z*w.z + a.w*w.w;
    }
    c_state = acc;
  }

  // ---------------- W_hh fragments -> registers (once) ----------------
  f16x8 whh_hi[16], whh_lo[16];
  #pragma unroll
  for (int kc = 0; kc < 16; ++kc){
    const float* p = W_hh + RW * 512 + kc * 32 + g * 8;
    float4 f0 = *(const float4*)p;
    float4 f1 = *(const float4*)(p + 4);
    float fs[8] = {f0.x,f0.y,f0.z,f0.w,f1.x,f1.y,f1.z,f1.w};
    short8 hb8, lb8;
    #pragma unroll
    for (int i = 0; i < 8; ++i){
      unsigned short hh, ll; split_f16(fs[i], hh, ll);
      hb8[i] = (short)hh; lb8[i] = (short)ll;
    }
    whh_hi[kc] = __builtin_bit_cast(f16x8, hb8);
    whh_lo[kc] = __builtin_bit_cast(f16x8, lb8);
  }

  const float bias_i = b_ih[j_own]        + b_hh[j_own];
  const float bias_f = b_ih[512 + j_own]  + b_hh[512 + j_own];
  const float bias_g = b_ih[1024 + j_own] + b_hh[1024 + j_own];
  const float bias_o = b_ih[1536 + j_own] + b_hh[1536 + j_own];

  // ---------------- one-time barrier: x f16 conversion complete ----------------
  asm volatile("s_waitcnt vmcnt(0)" ::: "memory");
  __syncthreads();
  if (tid == 0){
    unsigned one = 1;
    asm volatile("global_store_dword %0, %1, off sc0 sc1" :: "v"(flags + bid), "v"(one) : "memory");
  }
  {
    const unsigned* fp = flags + lane;
    while (true){
      unsigned fv;
      asm volatile("global_load_dword %0, %1, off sc0 sc1\n\ts_waitcnt vmcnt(0)"
                   : "=v"(fv) : "v"(fp) : "memory");
      if (__all((int)(fv >= 1u))) break;
      __builtin_amdgcn_s_sleep(1);
    }
  }

  // persistent x@W_ih prefix-sum accumulators (C-operand IS the cumsum)
  f32x4 axc0 = {0.f,0.f,0.f,0.f}, axc1 = axc0, axc2 = axc0;

  auto cvt8 = [](float4 f0, float4 f1, f16x8& hi, f16x8& lo){
    float fs[8] = {f0.x,f0.y,f0.z,f0.w,f1.x,f1.y,f1.z,f1.w};
    short8 hb8, lb8;
    #pragma unroll
    for (int i = 0; i < 8; ++i){
      unsigned short hh, ll; split_f16(fs[i], hh, ll);
      hb8[i] = (short)hh; lb8[i] = (short)ll;
    }
    hi = __builtin_bit_cast(f16x8, hb8);
    lo = __builtin_bit_cast(f16x8, lb8);
  };

  // step-0 x-part (cold, serial once)
  {
    #pragma unroll
    for (int kc = 0; kc < 2; ++kc){
      const float* p = W_ih + (size_t)RW * 16384 + kc * 32 + g * 8;
      f16x8 ahi, alo;
      cvt8(*(const float4*)p, *(const float4*)(p + 4), ahi, alo);
      size_t off = (size_t)b_own * 16384 + kc * 32 + g * 8;
      f16x8 bhi = __builtin_bit_cast(f16x8, *(const short8*)(xhi + off));
      f16x8 blo = __builtin_bit_cast(f16x8, *(const short8*)(xlo + off));
      axc0 = __builtin_amdgcn_mfma_f32_16x16x32_f16(ahi, bhi, axc0, 0,0,0);
      axc1 = __builtin_amdgcn_mfma_f32_16x16x32_f16(ahi, blo, axc1, 0,0,0);
      axc2 = __builtin_amdgcn_mfma_f32_16x16x32_f16(alo, bhi, axc2, 0,0,0);
    }
  }

  const int bbase = b_own << 6;        // 16B-unit base of B-frag row
  const int bb    = b_own & 7;

  for (int t = 0; t < 256; ++t){
    const unsigned* hb = hsteps + (size_t)t * 16384;
    uint4 d[16];

    // ---- poll h(t): block-collective 64KB tile, bulk issue + single wait ----
    while (true){
      #pragma unroll
      for (int k = 0; k < 8; ++k){
        const unsigned* p = hb + (size_t)(tid + k*256) * 8;
        asm volatile("global_load_dwordx4 %0, %1, off sc0 sc1" : "=v"(d[2*k])   : "v"(p));
        asm volatile("global_load_dwordx4 %0, %1, off sc0 sc1" : "=v"(d[2*k+1]) : "v"(p+4));
      }
      asm volatile("s_waitcnt vmcnt(0)" ::: "memory");
      __builtin_amdgcn_sched_barrier(0);
      unsigned mx = 0u;
      #pragma unroll
      for (int k = 0; k < 16; ++k){
        unsigned a  = d[k].x > d[k].y ? d[k].x : d[k].y;
        unsigned b2 = d[k].z > d[k].w ? d[k].z : d[k].w;
        unsigned c2 = a > b2 ? a : b2;
        mx = mx > c2 ? mx : c2;
      }
      if (__all((int)(mx != 0xFFFFFFFFu))) break;
      __builtin_amdgcn_s_sleep(1);
    }

    // ---- prefetch W_ih(t+1) + x(t+1) fragments NOW (plain cached loads);
    //      the surrounding asm-"memory" ops pin issue into this window ----
    float4 w0, w1, w2, w3;
    short8 xh0, xh1, xl0, xl1;
    if (t < 255){
      const float* p = W_ih + (size_t)RW * 16384 + (size_t)(t+1) * 64 + g * 8;
      w0 = *(const float4*)p;        w1 = *(const float4*)(p + 4);
      w2 = *(const float4*)(p + 32); w3 = *(const float4*)(p + 36);
      size_t off = ((size_t)b_own * 256 + (size_t)(t+1)) * 64 + g * 8;
      xh0 = *(const short8*)(xhi + off);      xh1 = *(const short8*)(xhi + off + 32);
      xl0 = *(const short8*)(xlo + off);      xl1 = *(const short8*)(xlo + off + 32);
    }

    // ---- unpack hi/lo (v_perm) + swizzled LDS write, buffer t&1 ----
    {
      unsigned short* dstH = &hs_hi[t & 1][0];
      unsigned short* dstL = &hs_lo[t & 1][0];
      #pragma unroll
      for (int k = 0; k < 8; ++k){
        int U = tid + k * 256;
        int b = U >> 6, u = U & 63;
        int us = u ^ (b & 7);
        uint4 d0 = d[2*k], d1 = d[2*k+1];
        uint4 hi4, lo4;
        hi4.x = __builtin_amdgcn_perm(d0.y, d0.x, 0x07060302u);
        hi4.y = __builtin_amdgcn_perm(d0.w, d0.z, 0x07060302u);
        hi4.z = __builtin_amdgcn_perm(d1.y, d1.x, 0x07060302u);
        hi4.w = __builtin_amdgcn_perm(d1.w, d1.z, 0x07060302u);
        lo4.x = __builtin_amdgcn_perm(d0.y, d0.x, 0x05040100u);
        lo4.y = __builtin_amdgcn_perm(d0.w, d0.z, 0x05040100u);
        lo4.z = __builtin_amdgcn_perm(d1.y, d1.x, 0x05040100u);
        lo4.w = __builtin_amdgcn_perm(d1.w, d1.z, 0x05040100u);
        *(uint4*)(dstH + (size_t)((b << 6) + us) * 8) = hi4;
        *(uint4*)(dstL + (size_t)((b << 6) + us) * 8) = lo4;
      }
    }
    __syncthreads();   // the ONLY barrier per step

    // ---- h @ W_hh^T via MFMA, 3-term hi/lo split ----
    f32x4 acc0 = {0.f,0.f,0.f,0.f}, acc1 = acc0, acc2 = acc0;
    {
      const unsigned short* srcH = &hs_hi[t & 1][0];
      const unsigned short* srcL = &hs_lo[t & 1][0];
      #pragma unroll
      for (int kc = 0; kc < 16; ++kc){
        int us = ((kc << 2) + g) ^ bb;
        f16x8 bhi = __builtin_bit_cast(f16x8, *(const short8*)(srcH + ((bbase + us) << 3)));
        f16x8 blo = __builtin_bit_cast(f16x8, *(const short8*)(srcL + ((bbase + us) << 3)));
        acc0 = __builtin_amdgcn_mfma_f32_16x16x32_f16(whh_hi[kc], bhi, acc0, 0,0,0);
        acc1 = __builtin_amdgcn_mfma_f32_16x16x32_f16(whh_hi[kc], blo, acc1, 0,0,0);
        acc2 = __builtin_amdgcn_mfma_f32_16x16x32_f16(whh_lo[kc], bhi, acc2, 0,0,0);
      }
    }

    // ---- gates entirely in-thread (acc regs q=0..3 = i,f,g,o of (b_own, j_own)) ----
    f32x4 pre = acc0 + acc1 + acc2 + axc0 + axc1 + axc2;
    float ig = fsig(pre[0] + bias_i);
    float fg = fsig(pre[1] + bias_f);
    float gg = ftanh(pre[2] + bias_g);
    float og = fsig(pre[3] + bias_o);
    c_state = fg * c_state + ig * gg;
    float hval = og * ftanh(c_state);

    if (t < 255){
      unsigned short hh, ll; split_f16(hval, hh, ll);
      unsigned packed = ((unsigned)hh << 16) | (unsigned)ll;   // finite => hi16 != 0xFFFF
      asm volatile("global_store_dword %0, %1, off sc0 sc1"
                   :: "v"(hsteps + (size_t)(t+1)*16384 + (size_t)b_own*512 + j_own), "v"(packed) : "memory");
    }
    out[(size_t)(b_own * 256 + t) * 512 + j_own] = fmaxf(hval, 0.f);

    // ---- x-part(t+1): prefetched regs -> convert + 6 MFMA (no memory wait) ----
    if (t < 255){
      f16x8 ahi0, alo0, ahi1, alo1;
      cvt8(w0, w1, ahi0, alo0);
      cvt8(w2, w3, ahi1, alo1);
      f16x8 bh0 = __builtin_bit_cast(f16x8, xh0), bl0 = __builtin_bit_cast(f16x8, xl0);
      f16x8 bh1 = __builtin_bit_cast(f16x8, xh1), bl1 = __builtin_bit_cast(f16x8, xl1);
      axc0 = __builtin_amdgcn_mfma_f32_16x16x32_f16(ahi0, bh0, axc0, 0,0,0);
      axc1 = __builtin_amdgcn_mfma_f32_16x16x32_f16(ahi0, bl0, axc1, 0,0,0);
      axc2 = __builtin_amdgcn_mfma_f32_16x16x32_f16(alo0, bh0, axc2, 0,0,0);
      axc0 = __builtin_amdgcn_mfma_f32_16x16x32_f16(ahi1, bh1, axc0, 0,0,0);
      axc1 = __builtin_amdgcn_mfma_f32_16x16x32_f16(ahi1, bl1, axc1, 0,0,0);
      axc2 = __builtin_amdgcn_mfma_f32_16x16x32_f16(alo1, bh1, axc2, 0,0,0);
    }
  }
}

// ---------------------------------------------------------------------------
extern "C" void kernel_launch(void* const* d_in, const int* in_sizes, int n_in,
                              void* d_out, int out_size, void* d_ws, size_t ws_size,
                              hipStream_t stream) {
  const float* x       = (const float*)d_in[0];
  const float* hidden0 = (const float*)d_in[1];
  const float* W_hid   = (const float*)d_in[2];
  const float* b_hid   = (const float*)d_in[3];
  const float* W_ih    = (const float*)d_in[4];
  const float* W_hh    = (const float*)d_in[5];
  const float* b_ih    = (const float*)d_in[6];
  const float* b_hh    = (const float*)d_in[7];

  float* out    = (float*)d_out;
  float* out_h0 = out + (size_t)32 * 256 * 512;

  char* ws = (char*)d_ws;
  unsigned*       flags  = (unsigned*)ws;                          // 256 B
  unsigned short* xhi    = (unsigned short*)(ws + 4096);           // 1 MB
  unsigned short* xlo    = (unsigned short*)(ws + 4096 + (1<<20)); // 1 MB
  unsigned*       hsteps = (unsigned*)(ws + 4096 + (2<<20));       // 16 MB: [256][32][512] dwords

  (void)hipMemsetAsync(flags, 0, 256, stream);
  (void)hipMemsetAsync(hsteps, 0xFF, (size_t)256 * 16384 * 4, stream);  // sentinel

  lstm_persist<<<NBLK, 256, 0, stream>>>(
      x, hidden0, W_hid, b_hid, W_ih, W_hh, b_ih, b_hh,
      out, out_h0, flags, hsteps, xhi, xlo);
}